// Round 2
// baseline (199.679 us; speedup 1.0000x reference)
//
#include <hip/hip_runtime.h>
#include <hip/hip_bf16.h>
#include <math.h>
#include <float.h>

// Problem constants (fixed by setup_inputs)
#define BATCH 108
#define NNODE 392
#define IDIM  256
#define HEADS 4
#define ODIM  64
#define HO    256            // HEADS*ODIM
#define MROWS (BATCH*NNODE)  // 42336
#define SGH   (BATCH*HEADS*NNODE)  // 169344

typedef __attribute__((ext_vector_type(8))) short bf16x8;
typedef __attribute__((ext_vector_type(8))) unsigned short u16x8;
typedef __attribute__((ext_vector_type(4))) float f32x4;

// exact RNE f32->bf16 (known-good; do NOT replace with v_cvt_pk_bf16_f32 —
// R1 showed that instruction's rounding breaks the absmax check: 7.6e-2 vs 7.8e-3)
__device__ __forceinline__ ushort f2bf(float f) {
    unsigned u = __float_as_uint(f);
    unsigned r = (u + 0x7FFFu + ((u >> 16) & 1u)) >> 16;   // RNE
    return (ushort)r;
}
__device__ __forceinline__ float bf2f(ushort h) {
    return __uint_as_float(((unsigned)h) << 16);
}
// fast sigmoid: v_mul + v_exp + v_add + v_rcp (replaces ocml expf + IEEE div;
// relative error ~1e-6, negligible vs bf16 rounding downstream)
__device__ __forceinline__ float fsigmoid(float x) {
    float e = __expf(-x);
    return __builtin_amdgcn_rcpf(1.0f + e);
}

#define MSTR 264   // LDS row stride (256 + 8 pad)

// ---------------------------------------------------------------------------
// Fused double-GEMM: 512 threads = 8 waves; wave (wg,wr) = head wg, row-half
// wr. Weights pre-shuffled to MFMA fragment order in HBM/L2, register
// double-buffered. x staged once to LDS; Ms aliases it. 3 barriers total.
__global__ __launch_bounds__(512)
void fused_gemm(const float* __restrict__ x, const ushort* __restrict__ wshuf,
                const ushort* __restrict__ kshuf, const float* __restrict__ bmlp,
                float* __restrict__ zbacc, ushort* __restrict__ xp0,
                const float* __restrict__ askv, const float* __restrict__ ankv,
                float* __restrict__ s0, float* __restrict__ ng0)
{
    __shared__ __attribute__((aligned(16))) ushort AsMs[64 * MSTR]; // x bf16 / mlp bf16

    const int t    = threadIdx.x;
    const int lane = t & 63;
    const int w    = t >> 6;            // 0..7
    const int wg   = w & 3;             // col-group / head
    const int wr   = w >> 2;            // row-half
    const int lr   = lane & 15, kq = lane >> 4;
    const int rb   = blockIdx.x;        // 0..6 row-block within batch
    const int b    = blockIdx.y;
    const int row0 = rb * 64;
    const long gbase = (long)b * NNODE;

    // ---- stage whole 64x256 x block (fp32 -> bf16), coalesced ----
    {
        const float* xb = x + (gbase + row0) * 256;
        #pragma unroll
        for (int j = 0; j < 8; ++j) {
            int e4  = t + j * 512;
            int row = e4 >> 6;
            int col = (e4 & 63) * 4;
            float4 v = (row0 + row < NNODE)
                ? *(const float4*)(xb + (long)row * 256 + col)
                : make_float4(0.f, 0.f, 0.f, 0.f);
            *(ushort4*)&AsMs[row * MSTR + col] =
                make_ushort4(f2bf(v.x), f2bf(v.y), f2bf(v.z), f2bf(v.w));
        }
    }
    __syncthreads();                        // barrier 1

    f32x4 acc[4][2] = {};   // [jn][imL]

    // ---------------- phase 1: mlp = sigmoid(x @ W + b) ----------------
    {
        bf16x8 wfn[4];
        #pragma unroll
        for (int jn = 0; jn < 4; ++jn)
            wfn[jn] = *(const bf16x8*)
                (wshuf + (((wg * 4 + jn) * 8 + 0) << 9) + lane * 8);
        #pragma unroll
        for (int k0t = 0; k0t < 8; ++k0t) {
            bf16x8 wfc[4];
            #pragma unroll
            for (int jn = 0; jn < 4; ++jn) wfc[jn] = wfn[jn];
            if (k0t < 7) {
                #pragma unroll
                for (int jn = 0; jn < 4; ++jn)
                    wfn[jn] = *(const bf16x8*)
                        (wshuf + (((wg * 4 + jn) * 8 + k0t + 1) << 9) + lane * 8);
            }
            bf16x8 xf[2];
            #pragma unroll
            for (int imL = 0; imL < 2; ++imL)
                xf[imL] = *(const bf16x8*)
                    &AsMs[(32 * wr + 16 * imL + lr) * MSTR + k0t * 32 + kq * 8];
            #pragma unroll
            for (int jn = 0; jn < 4; ++jn)
                #pragma unroll
                for (int imL = 0; imL < 2; ++imL)
                    acc[jn][imL] = __builtin_amdgcn_mfma_f32_16x16x32_bf16(
                        wfc[jn], xf[imL], acc[jn][imL], 0, 0, 0);
        }
    }
    __syncthreads();                        // barrier 2

    // ---- epilogue 1: sigmoid -> Ms (aliases x); col sums -> zbacc ----
    {
        float4 bi[4];
        #pragma unroll
        for (int jn = 0; jn < 4; ++jn)
            bi[jn] = *(const float4*)(bmlp + 64 * wg + 16 * jn + 4 * kq);
        float cs[4][4] = {};
        #pragma unroll
        for (int imL = 0; imL < 2; ++imL) {
            const int r_ = 32 * wr + 16 * imL + lr;
            const bool ok = row0 + r_ < NNODE;
            #pragma unroll
            for (int jn = 0; jn < 4; ++jn) {
                float v[4];
                v[0] = fsigmoid(acc[jn][imL][0] + bi[jn].x);
                v[1] = fsigmoid(acc[jn][imL][1] + bi[jn].y);
                v[2] = fsigmoid(acc[jn][imL][2] + bi[jn].z);
                v[3] = fsigmoid(acc[jn][imL][3] + bi[jn].w);
                *(ushort4*)&AsMs[r_ * MSTR + 64 * wg + 16 * jn + 4 * kq] =
                    make_ushort4(f2bf(v[0]), f2bf(v[1]), f2bf(v[2]), f2bf(v[3]));
                if (ok) {
                    cs[jn][0] += v[0]; cs[jn][1] += v[1];
                    cs[jn][2] += v[2]; cs[jn][3] += v[3];
                }
            }
        }
        #pragma unroll
        for (int jn = 0; jn < 4; ++jn)
            #pragma unroll
            for (int r = 0; r < 4; ++r) {
                float v = cs[jn][r];
                v += __shfl_xor(v, 1, 64);
                v += __shfl_xor(v, 2, 64);
                v += __shfl_xor(v, 4, 64);
                v += __shfl_xor(v, 8, 64);
                cs[jn][r] = v;
            }
        if (lr == 0) {
            #pragma unroll
            for (int jn = 0; jn < 4; ++jn)
                #pragma unroll
                for (int r = 0; r < 4; ++r)
                    atomicAdd(&zbacc[b * 256 + 64 * wg + 16 * jn + 4 * kq + r],
                              cs[jn][r]);
        }
    }
    __syncthreads();                        // barrier 3

    // ---------------- phase 2: xp0 = 0.2 * (Ms @ K^T) ----------------
    #pragma unroll
    for (int jn = 0; jn < 4; ++jn)
        #pragma unroll
        for (int imL = 0; imL < 2; ++imL)
            acc[jn][imL] = f32x4{0.f, 0.f, 0.f, 0.f};

    {
        bf16x8 wfn[4];
        #pragma unroll
        for (int jn = 0; jn < 4; ++jn)
            wfn[jn] = *(const bf16x8*)
                (kshuf + (((wg * 4 + jn) * 8 + 0) << 9) + lane * 8);
        #pragma unroll
        for (int k0t = 0; k0t < 8; ++k0t) {
            bf16x8 wfc[4];
            #pragma unroll
            for (int jn = 0; jn < 4; ++jn) wfc[jn] = wfn[jn];
            if (k0t < 7) {
                #pragma unroll
                for (int jn = 0; jn < 4; ++jn)
                    wfn[jn] = *(const bf16x8*)
                        (kshuf + (((wg * 4 + jn) * 8 + k0t + 1) << 9) + lane * 8);
            }
            bf16x8 xf[2];
            #pragma unroll
            for (int imL = 0; imL < 2; ++imL)
                xf[imL] = *(const bf16x8*)
                    &AsMs[(32 * wr + 16 * imL + lr) * MSTR + k0t * 32 + kq * 8];
            #pragma unroll
            for (int jn = 0; jn < 4; ++jn)
                #pragma unroll
                for (int imL = 0; imL < 2; ++imL)
                    acc[jn][imL] = __builtin_amdgcn_mfma_f32_16x16x32_bf16(
                        wfc[jn], xf[imL], acc[jn][imL], 0, 0, 0);
        }
    }

    // ---- epilogue 2: xp0 stores + fused s0/ng0 projections ----
    {
        const int h = wg;
        float askr[4][4], ankr[4][4];
        #pragma unroll
        for (int jn = 0; jn < 4; ++jn)
            #pragma unroll
            for (int r = 0; r < 4; ++r) {
                int o = 16 * jn + 4 * kq + r;
                askr[jn][r] = askv[o * HEADS + h];
                ankr[jn][r] = ankv[o * HEADS + h];
            }
        #pragma unroll
        for (int imL = 0; imL < 2; ++imL) {
            const int r_ = 32 * wr + 16 * imL + lr;
            const int lrow = row0 + r_;
            const bool ok = lrow < NNODE;
            float ps = 0.0f, pn = 0.0f;
            if (ok) {
                ushort* dst = xp0 + (gbase + lrow) * 256 + 64 * h + 4 * kq;
                #pragma unroll
                for (int jn = 0; jn < 4; ++jn) {
                    float v0 = 0.2f * acc[jn][imL][0];
                    float v1 = 0.2f * acc[jn][imL][1];
                    float v2 = 0.2f * acc[jn][imL][2];
                    float v3 = 0.2f * acc[jn][imL][3];
                    *(ushort4*)(dst + 16 * jn) =
                        make_ushort4(f2bf(v0), f2bf(v1), f2bf(v2), f2bf(v3));
                    ps += v0 * askr[jn][0] + v1 * askr[jn][1] +
                          v2 * askr[jn][2] + v3 * askr[jn][3];
                    pn += v0 * ankr[jn][0] + v1 * ankr[jn][1] +
                          v2 * ankr[jn][2] + v3 * ankr[jn][3];
                }
            }
            ps += __shfl_xor(ps, 16, 64);
            ps += __shfl_xor(ps, 32, 64);
            pn += __shfl_xor(pn, 16, 64);
            pn += __shfl_xor(pn, 32, 64);
            if (ok && kq == 0) {
                long si = ((long)b * HEADS + h) * NNODE + lrow;
                s0[si]  = ps;
                ng0[si] = pn;
            }
        }
    }
}

// ---------------------------------------------------------------------------
// Weight transpose + bf16 + MFMA-fragment shuffle; also zeroes zbacc
// (blocks 0..107 cover BATCH*IDIM = 27648 floats) -> saves a memset dispatch.
__global__ __launch_bounds__(256)
void wcvt(const float* __restrict__ w_mlp, const float* __restrict__ kern,
          ushort* __restrict__ wshuf, ushort* __restrict__ kshuf,
          float* __restrict__ zbacc)
{
    if (blockIdx.x < BATCH)
        zbacc[blockIdx.x * 256 + threadIdx.x] = 0.0f;
    long idx = (long)(blockIdx.x & 255) * 256 + threadIdx.x;   // 0..65535
    const float* src = (blockIdx.x < 256) ? w_mlp : kern;
    ushort* dst = (blockIdx.x < 256) ? wshuf : kshuf;
    int e    = idx & 7;
    int lane = (int)(idx >> 3) & 63;
    int k0t  = (int)(idx >> 9) & 7;
    int jn   = (int)(idx >> 12) & 3;
    int g    = (int)(idx >> 14);
    int n = 64 * g + 16 * jn + (lane & 15);
    int k = 32 * k0t + (lane >> 4) * 8 + e;
    dst[idx] = f2bf(src[(long)k * 256 + n]);
}

// ---------------------------------------------------------------------------
// zbK[b,c] = (0.8/N * zbacc[b]) @ kernel; also per-(b,h) projection consts.
// 1024 threads: k split into 4 chunks of 64 (4x the TLP of the 256-thread
// version; the serial k-loop drops 256 -> 64 iterations).
__global__ __launch_bounds__(1024)
void zbk_k(const float* __restrict__ zbacc, const float* __restrict__ kern,
           const float* __restrict__ askv, const float* __restrict__ ankv,
           float* __restrict__ zbK, float* __restrict__ sb,
           float* __restrict__ ngb)
{
    __shared__ float zrow[IDIM];
    __shared__ float part[4][IDIM];
    const int b = blockIdx.x, t = threadIdx.x;
    if (t < IDIM) zrow[t] = zbacc[b * 256 + t] * (0.8f / (float)NNODE);
    __syncthreads();
    const int c = t & 255, kc = t >> 8;
    float acc = 0.0f;
    #pragma unroll
    for (int kk = 0; kk < 64; ++kk) {
        int k = kc * 64 + kk;
        acc = fmaf(zrow[k], kern[(long)k * HO + c], acc);
    }
    part[kc][c] = acc;
    __syncthreads();
    if (t < IDIM) {
        float a = part[0][t] + part[1][t] + part[2][t] + part[3][t];
        zbK[b * 256 + t] = a;
        int h = t >> 6, o = t & 63;
        float ps = a * askv[o * HEADS + h];
        float pn = a * ankv[o * HEADS + h];
        #pragma unroll
        for (int off = 32; off; off >>= 1) {
            ps += __shfl_down(ps, off, 64);
            pn += __shfl_down(pn, off, 64);
        }
        if (o == 0) {
            sb[b * HEADS + h]  = ps;
            ngb[b * HEADS + h] = pn;
        }
    }
}

// ---------------------------------------------------------------------------
// attn_stats: per (b,h): keys = ng0 + ngb[bh], bitonic sort, denominator
// scans, per-row threshold; perm+threshold packed. 512 threads.
__global__ __launch_bounds__(512)
void attn_stats(const float* __restrict__ s0, const float* __restrict__ ng0,
                const float* __restrict__ sb, const float* __restrict__ ngb,
                uint* __restrict__ ptG, float2* __restrict__ w12G,
                float2* __restrict__ g12G)
{
    __shared__ float key[512];
    __shared__ int   perm[512];
    __shared__ float w1[NNODE], w2[NNODE];
    __shared__ float D1[NNODE + 1], D2[NNODE + 1];
    __shared__ float CT1[16], CT2[16];

    const int t = threadIdx.x;
    const int bh = blockIdx.x;
    const long base = (long)bh * NNODE;
    const float ngc = ngb[bh], sc = sb[bh];

    key[t]  = (t < NNODE) ? (ng0[base + t] + ngc) : FLT_MAX;
    perm[t] = t;
    __syncthreads();

    for (int k = 2; k <= 512; k <<= 1) {
        for (int j = k >> 1; j > 0; j >>= 1) {
            int l = t ^ j;
            if (l > t) {
                bool dir = ((t & k) == 0);
                float ki = key[t], kl = key[l];
                if ((ki > kl) == dir) {
                    key[t] = kl; key[l] = ki;
                    int pi = perm[t]; perm[t] = perm[l]; perm[l] = pi;
                }
            }
            __syncthreads();
        }
    }

    if (t < NNODE) {
        w1[t] = __expf(key[t]);
        w2[t] = __expf(0.2f * key[t]);
    }
    __syncthreads();

    if (t < 16) {
        float a1 = 0.0f;
        for (int jj = 24; jj >= 0; --jj) {
            int j = t * 25 + jj;
            if (j < NNODE) { a1 += w1[j]; D1[j] = a1; }
        }
        CT1[t] = a1;
    } else if (t < 32) {
        int c = t - 16;
        float a2 = 0.0f;
        for (int jj = 0; jj < 25; ++jj) {
            int j = c * 25 + jj;
            if (j < NNODE) { D2[j] = a2; a2 += w2[j]; }
        }
        CT2[c] = a2;
    }
    __syncthreads();
    if (t < 16) {
        float off = 0.0f;
        for (int cc = t + 1; cc < 16; ++cc) off += CT1[cc];
        for (int jj = 0; jj < 25; ++jj) {
            int j = t * 25 + jj;
            if (j < NNODE) D1[j] += off;
        }
    } else if (t < 32) {
        int c = t - 16;
        float off = 0.0f;
        for (int cc = 0; cc < c; ++cc) off += CT2[cc];
        for (int jj = 0; jj < 25; ++jj) {
            int j = c * 25 + jj;
            if (j < NNODE) D2[j] += off;
        }
    } else if (t == 32) {
        D1[NNODE] = 0.0f;
    } else if (t == 33) {
        float tot = 0.0f;
        for (int cc = 0; cc < 16; ++cc) tot += CT2[cc];
        D2[NNODE] = tot;
    }
    __syncthreads();

    if (t < NNODE) {
        float sn = s0[base + t] + sc;
        float negs = -sn;
        int lo = 0, hi = NNODE;
        while (lo < hi) {
            int mid = (lo + hi) >> 1;
            if (key[mid] < negs) lo = mid + 1; else hi = mid;
        }
        float e1 = __expf(sn), e2 = __expf(0.2f * sn);
        float inv = __builtin_amdgcn_rcpf(e1 * D1[lo] + e2 * D2[lo]);
        ptG[base + t]  = (uint)perm[t] | ((uint)lo << 16);
        g12G[base + t] = make_float2(e1 * inv, e2 * inv);
        w12G[base + t] = make_float2(w1[t], w2[t]);
    }
}

// ---------------------------------------------------------------------------
// attn_scan: block = (og, bh); 16 o-cols, 1024 threads = 64 chunks x 16.
// 32 B/row gather, column-major LDS. Cross-chunk offsets via 6-step
// Hillis-Steele tree scans over CT (replaces 63-deep serial LDS loops).
// out = elu(g1*S1[t] + g2*S2[t] + zbK[b][col] + bias).
#define CHN 7    // chunk depth: 64*7 = 448 >= 392
#define NP  (NNODE + 1)
__global__ __launch_bounds__(1024)
void attn_scan(const ushort* __restrict__ xp, const uint* __restrict__ ptG,
               const float2* __restrict__ w12G, const float2* __restrict__ g12G,
               const float* __restrict__ zbK, const float* __restrict__ bias,
               float* __restrict__ out)
{
    __shared__ float  Vs[16 * NP];
    __shared__ float  S1[16 * NP];
    __shared__ float  w1s[NNODE], w2s[NNODE], g1s[NNODE], g2s[NNODE];
    __shared__ ushort perms[NNODE], tls[NNODE];
    __shared__ float  CT[64][17], CT2[64][17];
    __shared__ float  biasl[16];

    const int t  = threadIdx.x;
    const int og = blockIdx.x;          // 0..3
    const int bh = blockIdx.y;          // 0..431
    const int b  = bh >> 2, h = bh & 3;
    const long base = (long)bh * NNODE;
    const int c0 = h * 64 + og * 16;

    if (t < NNODE) {
        uint pt = ptG[base + t];
        perms[t] = (ushort)(pt & 0xFFFFu);
        tls[t]   = (ushort)(pt >> 16);
        float2 w = w12G[base + t];
        w1s[t] = w.x; w2s[t] = w.y;
    } else if (t >= 512 && t < 512 + NNODE) {
        int i = t - 512;
        float2 g = g12G[base + i];
        g1s[i] = g.x; g2s[i] = g.y;
    }
    if (t < 16) biasl[t] = bias[c0 + t] + zbK[b * 256 + c0 + t];
    __syncthreads();

    // gather: 2 x uint4 (8 bf16 each) per sorted row; column-major scatter
    if (t < NNODE * 2) {
        int j = t >> 1, q = (t & 1) * 8;
        int m = perms[j];
        u16x8 raw = *(const u16x8*)(xp + ((long)b * NNODE + m) * HO + c0 + q);
        #pragma unroll
        for (int oo = 0; oo < 8; ++oo) Vs[(q + oo) * NP + j] = bf2f(raw[oo]);
    }
    __syncthreads();

    const int c = t >> 4, o = t & 15;   // 64 chunks x 16 cols

    // S1: w1-weighted suffix sums within chunk
    {
        float acc = 0.0f;
        #pragma unroll
        for (int jj = CHN - 1; jj >= 0; --jj) {
            int j = c * CHN + jj;
            if (j < NNODE) {
                acc = fmaf(w1s[j], Vs[o * NP + j], acc);
                S1[o * NP + j] = acc;
            }
        }
        CT[c][o] = acc;
    }
    __syncthreads();
    // tree-scan CT into inclusive SUFFIX sums over c (6 steps)
    #pragma unroll
    for (int s = 1; s < 64; s <<= 1) {
        float add = (c + s < 64) ? CT[c + s][o] : 0.0f;
        __syncthreads();
        CT[c][o] += add;
        __syncthreads();
    }
    {
        float off = (c < 63) ? CT[c + 1][o] : 0.0f;
        #pragma unroll
        for (int jj = 0; jj < CHN; ++jj) {
            int j = c * CHN + jj;
            if (j < NNODE) S1[o * NP + j] += off;
        }
        if (c == 0) S1[o * NP + NNODE] = 0.0f;
    }
    // S2: w2-weighted exclusive prefix within chunk, in place over Vs
    {
        float acc = 0.0f;
        #pragma unroll
        for (int jj = 0; jj < CHN; ++jj) {
            int j = c * CHN + jj;
            if (j < NNODE) {
                float tmp = Vs[o * NP + j];
                Vs[o * NP + j] = acc;
                acc = fmaf(w2s[j], tmp, acc);
            }
        }
        CT2[c][o] = acc;
    }
    __syncthreads();
    // tree-scan CT2 into inclusive PREFIX sums over c (6 steps)
    #pragma unroll
    for (int s = 1; s < 64; s <<= 1) {
        float add = (c >= s) ? CT2[c - s][o] : 0.0f;
        __syncthreads();
        CT2[c][o] += add;
        __syncthreads();
    }
    {
        float off = (c > 0) ? CT2[c - 1][o] : 0.0f;
        #pragma unroll
        for (int jj = 0; jj < CHN; ++jj) {
            int j = c * CHN + jj;
            if (j < NNODE) Vs[o * NP + j] += off;
        }
        if (c == 63) Vs[o * NP + NNODE] = CT2[63][o];
    }
    __syncthreads();

    // emit: float4 per (row, col-quad)
    for (int idx = t; idx < NNODE * 4; idx += 1024) {
        int n = idx >> 2, q = (idx & 3) * 4;
        int tt = tls[n];
        float g1 = g1s[n], g2 = g2s[n];
        float r[4];
        #pragma unroll
        for (int rr = 0; rr < 4; ++rr) {
            int oo = q + rr;
            float v = g1 * S1[oo * NP + tt] + g2 * Vs[oo * NP + tt] + biasl[oo];
            r[rr] = (v > 0.0f) ? v : (__expf(v) - 1.0f);
        }
        *(float4*)(out + ((long)b * NNODE + n) * HO + c0 + q) =
            make_float4(r[0], r[1], r[2], r[3]);
    }
}

extern "C" void kernel_launch(void* const* d_in, const int* in_sizes, int n_in,
                              void* d_out, int out_size, void* d_ws, size_t ws_size,
                              hipStream_t stream) {
    const float* x     = (const float*)d_in[0];   // [108,392,256]
    const float* w_mlp = (const float*)d_in[2];   // [256,256]
    const float* b_mlp = (const float*)d_in[3];   // [256]
    const float* kern  = (const float*)d_in[4];   // [256,4,64] == [256,256]
    const float* ask   = (const float*)d_in[5];   // [64,4,1]
    const float* ank   = (const float*)d_in[6];   // [64,4,1]
    const float* bias  = (const float*)d_in[7];   // [256]
    float* out = (float*)d_out;

    const long TENS = (long)MROWS * IDIM;         // 10,838,016
    float*  s0    = (float*)d_ws;                 // [B,H,N]
    float*  ng0   = s0 + SGH;
    float*  zbacc = ng0 + SGH;                    // [B,256] atomically built
    float*  zbK   = zbacc + (long)BATCH * IDIM;   // [B,256]
    float*  sb    = zbK + (long)BATCH * HO;       // [B,H]
    float*  ngb   = sb + BATCH * HEADS;           // [B,H]
    float2* w12G  = (float2*)(ngb + BATCH * HEADS);
    float2* g12G  = w12G + SGH;
    uint*   ptG   = (uint*)(g12G + SGH);
    ushort* xp_bf = (ushort*)(ptG + SGH);         // [B,N,H*O] bf16 (xp0)
    ushort* wshuf = xp_bf + TENS;                 // [65536] frag-order w_mlp
    ushort* kshuf = wshuf + 65536;                // [65536] frag-order kernel

    dim3 blk(256);

    // 0) weight shuffle + zbacc zeroing (fused)
    wcvt<<<dim3(512), blk, 0, stream>>>(w_mlp, kern, wshuf, kshuf, zbacc);

    // 1) fused: mlp(sigmoid, LDS-only) -> col-sums -> xp0 + s0/ng0
    fused_gemm<<<dim3(7, BATCH), dim3(512), 0, stream>>>(
        x, wshuf, kshuf, b_mlp, zbacc, xp_bf, ask, ank, s0, ng0);

    // 2) zbK = (0.8*mean mlp) @ kernel + per-(b,h) projection constants
    zbk_k<<<dim3(BATCH), dim3(1024), 0, stream>>>(zbacc, kern, ask, ank, zbK, sb, ngb);

    // 3) attention stats: const-shifted sort + denominators + thresholds
    attn_stats<<<dim3(BATCH * HEADS), dim3(512), 0, stream>>>(
        s0, ng0, sb, ngb, ptG, w12G, g12G);

    // 4) attention scan: tree-scanned prefix/suffix sums + emit
    attn_scan<<<dim3(4, BATCH * HEADS), dim3(1024), 0, stream>>>(
        xp_bf, ptG, w12G, g12G, zbK, bias, out);
}

// Round 3
// 194.827 us; speedup vs baseline: 1.0249x; 1.0249x over previous
//
#include <hip/hip_runtime.h>
#include <hip/hip_bf16.h>
#include <math.h>
#include <float.h>

// Problem constants (fixed by setup_inputs)
#define BATCH 108
#define NNODE 392
#define IDIM  256
#define HEADS 4
#define ODIM  64
#define HO    256            // HEADS*ODIM
#define MROWS (BATCH*NNODE)  // 42336
#define SGH   (BATCH*HEADS*NNODE)  // 169344

typedef __attribute__((ext_vector_type(8))) short bf16x8;
typedef __attribute__((ext_vector_type(8))) unsigned short u16x8;
typedef __attribute__((ext_vector_type(4))) float f32x4;

// exact RNE f32->bf16 (known-good; do NOT replace with v_cvt_pk_bf16_f32 —
// R1 showed that instruction's rounding breaks the absmax check: 7.6e-2 vs 7.8e-3)
__device__ __forceinline__ ushort f2bf(float f) {
    unsigned u = __float_as_uint(f);
    unsigned r = (u + 0x7FFFu + ((u >> 16) & 1u)) >> 16;   // RNE
    return (ushort)r;
}
__device__ __forceinline__ float bf2f(ushort h) {
    return __uint_as_float(((unsigned)h) << 16);
}
// fast sigmoid: v_mul + v_exp + v_add + v_rcp (kept from R2: VALUBusy 31->20%)
__device__ __forceinline__ float fsigmoid(float x) {
    float e = __expf(-x);
    return __builtin_amdgcn_rcpf(1.0f + e);
}

#define MSTR 264   // LDS row stride (256 + 8 pad)

// ---------------------------------------------------------------------------
// Fused double-GEMM, R3 retile: 32 rows / 256 threads / 4 waves per block,
// grid 13x108 = 1404 blocks (~5.5/CU vs 2.95 before). R2 counters showed the
// 64-row version was latency-bound at 26% occupancy (MfmaUtil 9 + VALUBusy 20,
// grid-capped). Wave wg = head/col-group. Weight fragments prefetched above
// the preceding barrier to overlap global-load latency with staging/epilogue.
__global__ __launch_bounds__(256)
void fused_gemm(const float* __restrict__ x, const ushort* __restrict__ wshuf,
                const ushort* __restrict__ kshuf, const float* __restrict__ bmlp,
                float* __restrict__ zbacc, ushort* __restrict__ xp0,
                const float* __restrict__ askv, const float* __restrict__ ankv,
                float* __restrict__ s0, float* __restrict__ ng0)
{
    __shared__ __attribute__((aligned(16))) ushort AsMs[32 * MSTR]; // x bf16 / mlp bf16

    const int t    = threadIdx.x;
    const int lane = t & 63;
    const int wg   = t >> 6;            // 0..3 col-group / head
    const int lr   = lane & 15, kq = lane >> 4;
    const int rb   = blockIdx.x;        // 0..12 row-block within batch
    const int b    = blockIdx.y;
    const int row0 = rb * 32;
    const long gbase = (long)b * NNODE;

    // prefetch phase-1 first weight fragments (no LDS dep; overlaps x staging)
    bf16x8 wfn[4];
    #pragma unroll
    for (int jn = 0; jn < 4; ++jn)
        wfn[jn] = *(const bf16x8*)
            (wshuf + (((wg * 4 + jn) * 8 + 0) << 9) + lane * 8);

    // ---- stage 32x256 x block (fp32 -> bf16), coalesced ----
    {
        const float* xb = x + (gbase + row0) * 256;
        #pragma unroll
        for (int j = 0; j < 8; ++j) {
            int e4  = t + j * 256;
            int row = e4 >> 6;
            int col = (e4 & 63) * 4;
            float4 v = (row0 + row < NNODE)
                ? *(const float4*)(xb + (long)row * 256 + col)
                : make_float4(0.f, 0.f, 0.f, 0.f);
            *(ushort4*)&AsMs[row * MSTR + col] =
                make_ushort4(f2bf(v.x), f2bf(v.y), f2bf(v.z), f2bf(v.w));
        }
    }
    __syncthreads();                        // barrier 1

    f32x4 acc[4][2] = {};   // [jn][imL]

    // ---------------- phase 1: mlp = sigmoid(x @ W + b) ----------------
    {
        #pragma unroll
        for (int k0t = 0; k0t < 8; ++k0t) {
            bf16x8 wfc[4];
            #pragma unroll
            for (int jn = 0; jn < 4; ++jn) wfc[jn] = wfn[jn];
            if (k0t < 7) {
                #pragma unroll
                for (int jn = 0; jn < 4; ++jn)
                    wfn[jn] = *(const bf16x8*)
                        (wshuf + (((wg * 4 + jn) * 8 + k0t + 1) << 9) + lane * 8);
            }
            bf16x8 xf[2];
            #pragma unroll
            for (int imL = 0; imL < 2; ++imL)
                xf[imL] = *(const bf16x8*)
                    &AsMs[(16 * imL + lr) * MSTR + k0t * 32 + kq * 8];
            #pragma unroll
            for (int jn = 0; jn < 4; ++jn)
                #pragma unroll
                for (int imL = 0; imL < 2; ++imL)
                    acc[jn][imL] = __builtin_amdgcn_mfma_f32_16x16x32_bf16(
                        wfc[jn], xf[imL], acc[jn][imL], 0, 0, 0);
        }
    }

    // prefetch phase-2 first weight fragments (overlaps epilogue 1)
    bf16x8 kfn[4];
    #pragma unroll
    for (int jn = 0; jn < 4; ++jn)
        kfn[jn] = *(const bf16x8*)
            (kshuf + (((wg * 4 + jn) * 8 + 0) << 9) + lane * 8);

    __syncthreads();                        // barrier 2

    // ---- epilogue 1: sigmoid -> Ms (aliases x); col sums -> zbacc ----
    {
        float4 bi[4];
        #pragma unroll
        for (int jn = 0; jn < 4; ++jn)
            bi[jn] = *(const float4*)(bmlp + 64 * wg + 16 * jn + 4 * kq);
        float cs[4][4] = {};
        #pragma unroll
        for (int imL = 0; imL < 2; ++imL) {
            const int r_ = 16 * imL + lr;
            const bool ok = row0 + r_ < NNODE;
            #pragma unroll
            for (int jn = 0; jn < 4; ++jn) {
                float v[4];
                v[0] = fsigmoid(acc[jn][imL][0] + bi[jn].x);
                v[1] = fsigmoid(acc[jn][imL][1] + bi[jn].y);
                v[2] = fsigmoid(acc[jn][imL][2] + bi[jn].z);
                v[3] = fsigmoid(acc[jn][imL][3] + bi[jn].w);
                *(ushort4*)&AsMs[r_ * MSTR + 64 * wg + 16 * jn + 4 * kq] =
                    make_ushort4(f2bf(v[0]), f2bf(v[1]), f2bf(v[2]), f2bf(v[3]));
                if (ok) {
                    cs[jn][0] += v[0]; cs[jn][1] += v[1];
                    cs[jn][2] += v[2]; cs[jn][3] += v[3];
                }
            }
        }
        #pragma unroll
        for (int jn = 0; jn < 4; ++jn)
            #pragma unroll
            for (int r = 0; r < 4; ++r) {
                float v = cs[jn][r];
                v += __shfl_xor(v, 1, 64);
                v += __shfl_xor(v, 2, 64);
                v += __shfl_xor(v, 4, 64);
                v += __shfl_xor(v, 8, 64);
                cs[jn][r] = v;
            }
        if (lr == 0) {
            #pragma unroll
            for (int jn = 0; jn < 4; ++jn)
                #pragma unroll
                for (int r = 0; r < 4; ++r)
                    atomicAdd(&zbacc[b * 256 + 64 * wg + 16 * jn + 4 * kq + r],
                              cs[jn][r]);
        }
    }
    __syncthreads();                        // barrier 3

    // ---------------- phase 2: xp0 = 0.2 * (Ms @ K^T) ----------------
    #pragma unroll
    for (int jn = 0; jn < 4; ++jn)
        #pragma unroll
        for (int imL = 0; imL < 2; ++imL)
            acc[jn][imL] = f32x4{0.f, 0.f, 0.f, 0.f};

    {
        #pragma unroll
        for (int k0t = 0; k0t < 8; ++k0t) {
            bf16x8 wfc[4];
            #pragma unroll
            for (int jn = 0; jn < 4; ++jn) wfc[jn] = kfn[jn];
            if (k0t < 7) {
                #pragma unroll
                for (int jn = 0; jn < 4; ++jn)
                    kfn[jn] = *(const bf16x8*)
                        (kshuf + (((wg * 4 + jn) * 8 + k0t + 1) << 9) + lane * 8);
            }
            bf16x8 xf[2];
            #pragma unroll
            for (int imL = 0; imL < 2; ++imL)
                xf[imL] = *(const bf16x8*)
                    &AsMs[(16 * imL + lr) * MSTR + k0t * 32 + kq * 8];
            #pragma unroll
            for (int jn = 0; jn < 4; ++jn)
                #pragma unroll
                for (int imL = 0; imL < 2; ++imL)
                    acc[jn][imL] = __builtin_amdgcn_mfma_f32_16x16x32_bf16(
                        wfc[jn], xf[imL], acc[jn][imL], 0, 0, 0);
        }
    }

    // ---- epilogue 2: xp0 stores + fused s0/ng0 projections ----
    {
        const int h = wg;
        float askr[4][4], ankr[4][4];
        #pragma unroll
        for (int jn = 0; jn < 4; ++jn)
            #pragma unroll
            for (int r = 0; r < 4; ++r) {
                int o = 16 * jn + 4 * kq + r;
                askr[jn][r] = askv[o * HEADS + h];
                ankr[jn][r] = ankv[o * HEADS + h];
            }
        #pragma unroll
        for (int imL = 0; imL < 2; ++imL) {
            const int r_ = 16 * imL + lr;
            const int lrow = row0 + r_;
            const bool ok = lrow < NNODE;
            float ps = 0.0f, pn = 0.0f;
            if (ok) {
                ushort* dst = xp0 + (gbase + lrow) * 256 + 64 * h + 4 * kq;
                #pragma unroll
                for (int jn = 0; jn < 4; ++jn) {
                    float v0 = 0.2f * acc[jn][imL][0];
                    float v1 = 0.2f * acc[jn][imL][1];
                    float v2 = 0.2f * acc[jn][imL][2];
                    float v3 = 0.2f * acc[jn][imL][3];
                    *(ushort4*)(dst + 16 * jn) =
                        make_ushort4(f2bf(v0), f2bf(v1), f2bf(v2), f2bf(v3));
                    ps += v0 * askr[jn][0] + v1 * askr[jn][1] +
                          v2 * askr[jn][2] + v3 * askr[jn][3];
                    pn += v0 * ankr[jn][0] + v1 * ankr[jn][1] +
                          v2 * ankr[jn][2] + v3 * ankr[jn][3];
                }
            }
            ps += __shfl_xor(ps, 16, 64);
            ps += __shfl_xor(ps, 32, 64);
            pn += __shfl_xor(pn, 16, 64);
            pn += __shfl_xor(pn, 32, 64);
            if (ok && kq == 0) {
                long si = ((long)b * HEADS + h) * NNODE + lrow;
                s0[si]  = ps;
                ng0[si] = pn;
            }
        }
    }
}

// ---------------------------------------------------------------------------
// Weight transpose + bf16 + MFMA-fragment shuffle; also zeroes zbacc
// (blocks 0..107 cover BATCH*IDIM = 27648 floats) -> saves a memset dispatch.
__global__ __launch_bounds__(256)
void wcvt(const float* __restrict__ w_mlp, const float* __restrict__ kern,
          ushort* __restrict__ wshuf, ushort* __restrict__ kshuf,
          float* __restrict__ zbacc)
{
    if (blockIdx.x < BATCH)
        zbacc[blockIdx.x * 256 + threadIdx.x] = 0.0f;
    long idx = (long)(blockIdx.x & 255) * 256 + threadIdx.x;   // 0..65535
    const float* src = (blockIdx.x < 256) ? w_mlp : kern;
    ushort* dst = (blockIdx.x < 256) ? wshuf : kshuf;
    int e    = idx & 7;
    int lane = (int)(idx >> 3) & 63;
    int k0t  = (int)(idx >> 9) & 7;
    int jn   = (int)(idx >> 12) & 3;
    int g    = (int)(idx >> 14);
    int n = 64 * g + 16 * jn + (lane & 15);
    int k = 32 * k0t + (lane >> 4) * 8 + e;
    dst[idx] = f2bf(src[(long)k * 256 + n]);
}

// ---------------------------------------------------------------------------
// zbK[b,c] = (0.8/N * zbacc[b]) @ kernel; also per-(b,h) projection consts.
// 1024 threads: k split into 4 chunks of 64.
__global__ __launch_bounds__(1024)
void zbk_k(const float* __restrict__ zbacc, const float* __restrict__ kern,
           const float* __restrict__ askv, const float* __restrict__ ankv,
           float* __restrict__ zbK, float* __restrict__ sb,
           float* __restrict__ ngb)
{
    __shared__ float zrow[IDIM];
    __shared__ float part[4][IDIM];
    const int b = blockIdx.x, t = threadIdx.x;
    if (t < IDIM) zrow[t] = zbacc[b * 256 + t] * (0.8f / (float)NNODE);
    __syncthreads();
    const int c = t & 255, kc = t >> 8;
    float acc = 0.0f;
    #pragma unroll
    for (int kk = 0; kk < 64; ++kk) {
        int k = kc * 64 + kk;
        acc = fmaf(zrow[k], kern[(long)k * HO + c], acc);
    }
    part[kc][c] = acc;
    __syncthreads();
    if (t < IDIM) {
        float a = part[0][t] + part[1][t] + part[2][t] + part[3][t];
        zbK[b * 256 + t] = a;
        int h = t >> 6, o = t & 63;
        float ps = a * askv[o * HEADS + h];
        float pn = a * ankv[o * HEADS + h];
        #pragma unroll
        for (int off = 32; off; off >>= 1) {
            ps += __shfl_down(ps, off, 64);
            pn += __shfl_down(pn, off, 64);
        }
        if (o == 0) {
            sb[b * HEADS + h]  = ps;
            ngb[b * HEADS + h] = pn;
        }
    }
}

// ---------------------------------------------------------------------------
// attn_stats: per (b,h): keys = ng0 + ngb[bh], bitonic sort, denominator
// scans, per-row threshold; perm+threshold packed. 512 threads.
__global__ __launch_bounds__(512)
void attn_stats(const float* __restrict__ s0, const float* __restrict__ ng0,
                const float* __restrict__ sb, const float* __restrict__ ngb,
                uint* __restrict__ ptG, float2* __restrict__ w12G,
                float2* __restrict__ g12G)
{
    __shared__ float key[512];
    __shared__ int   perm[512];
    __shared__ float w1[NNODE], w2[NNODE];
    __shared__ float D1[NNODE + 1], D2[NNODE + 1];
    __shared__ float CT1[16], CT2[16];

    const int t = threadIdx.x;
    const int bh = blockIdx.x;
    const long base = (long)bh * NNODE;
    const float ngc = ngb[bh], sc = sb[bh];

    key[t]  = (t < NNODE) ? (ng0[base + t] + ngc) : FLT_MAX;
    perm[t] = t;
    __syncthreads();

    for (int k = 2; k <= 512; k <<= 1) {
        for (int j = k >> 1; j > 0; j >>= 1) {
            int l = t ^ j;
            if (l > t) {
                bool dir = ((t & k) == 0);
                float ki = key[t], kl = key[l];
                if ((ki > kl) == dir) {
                    key[t] = kl; key[l] = ki;
                    int pi = perm[t]; perm[t] = perm[l]; perm[l] = pi;
                }
            }
            __syncthreads();
        }
    }

    if (t < NNODE) {
        w1[t] = __expf(key[t]);
        w2[t] = __expf(0.2f * key[t]);
    }
    __syncthreads();

    if (t < 16) {
        float a1 = 0.0f;
        for (int jj = 24; jj >= 0; --jj) {
            int j = t * 25 + jj;
            if (j < NNODE) { a1 += w1[j]; D1[j] = a1; }
        }
        CT1[t] = a1;
    } else if (t < 32) {
        int c = t - 16;
        float a2 = 0.0f;
        for (int jj = 0; jj < 25; ++jj) {
            int j = c * 25 + jj;
            if (j < NNODE) { D2[j] = a2; a2 += w2[j]; }
        }
        CT2[c] = a2;
    }
    __syncthreads();
    if (t < 16) {
        float off = 0.0f;
        for (int cc = t + 1; cc < 16; ++cc) off += CT1[cc];
        for (int jj = 0; jj < 25; ++jj) {
            int j = t * 25 + jj;
            if (j < NNODE) D1[j] += off;
        }
    } else if (t < 32) {
        int c = t - 16;
        float off = 0.0f;
        for (int cc = 0; cc < c; ++cc) off += CT2[cc];
        for (int jj = 0; jj < 25; ++jj) {
            int j = c * 25 + jj;
            if (j < NNODE) D2[j] += off;
        }
    } else if (t == 32) {
        D1[NNODE] = 0.0f;
    } else if (t == 33) {
        float tot = 0.0f;
        for (int cc = 0; cc < 16; ++cc) tot += CT2[cc];
        D2[NNODE] = tot;
    }
    __syncthreads();

    if (t < NNODE) {
        float sn = s0[base + t] + sc;
        float negs = -sn;
        int lo = 0, hi = NNODE;
        while (lo < hi) {
            int mid = (lo + hi) >> 1;
            if (key[mid] < negs) lo = mid + 1; else hi = mid;
        }
        float e1 = __expf(sn), e2 = __expf(0.2f * sn);
        float inv = __builtin_amdgcn_rcpf(e1 * D1[lo] + e2 * D2[lo]);
        ptG[base + t]  = (uint)perm[t] | ((uint)lo << 16);
        g12G[base + t] = make_float2(e1 * inv, e2 * inv);
        w12G[base + t] = make_float2(w1[t], w2[t]);
    }
}

// ---------------------------------------------------------------------------
// attn_scan: block = (og, bh); 16 o-cols, 1024 threads = 64 chunks x 16.
// 32 B/row gather, column-major LDS. Cross-chunk offsets via 6-step
// Hillis-Steele tree scans over CT (replaces 63-deep serial LDS loops).
// out = elu(g1*S1[t] + g2*S2[t] + zbK[b][col] + bias).
#define CHN 7    // chunk depth: 64*7 = 448 >= 392
#define NP  (NNODE + 1)
__global__ __launch_bounds__(1024)
void attn_scan(const ushort* __restrict__ xp, const uint* __restrict__ ptG,
               const float2* __restrict__ w12G, const float2* __restrict__ g12G,
               const float* __restrict__ zbK, const float* __restrict__ bias,
               float* __restrict__ out)
{
    __shared__ float  Vs[16 * NP];
    __shared__ float  S1[16 * NP];
    __shared__ float  w1s[NNODE], w2s[NNODE], g1s[NNODE], g2s[NNODE];
    __shared__ ushort perms[NNODE], tls[NNODE];
    __shared__ float  CT[64][17], CT2[64][17];
    __shared__ float  biasl[16];

    const int t  = threadIdx.x;
    const int og = blockIdx.x;          // 0..3
    const int bh = blockIdx.y;          // 0..431
    const int b  = bh >> 2, h = bh & 3;
    const long base = (long)bh * NNODE;
    const int c0 = h * 64 + og * 16;

    if (t < NNODE) {
        uint pt = ptG[base + t];
        perms[t] = (ushort)(pt & 0xFFFFu);
        tls[t]   = (ushort)(pt >> 16);
        float2 w = w12G[base + t];
        w1s[t] = w.x; w2s[t] = w.y;
    } else if (t >= 512 && t < 512 + NNODE) {
        int i = t - 512;
        float2 g = g12G[base + i];
        g1s[i] = g.x; g2s[i] = g.y;
    }
    if (t < 16) biasl[t] = bias[c0 + t] + zbK[b * 256 + c0 + t];
    __syncthreads();

    // gather: 2 x uint4 (8 bf16 each) per sorted row; column-major scatter
    if (t < NNODE * 2) {
        int j = t >> 1, q = (t & 1) * 8;
        int m = perms[j];
        u16x8 raw = *(const u16x8*)(xp + ((long)b * NNODE + m) * HO + c0 + q);
        #pragma unroll
        for (int oo = 0; oo < 8; ++oo) Vs[(q + oo) * NP + j] = bf2f(raw[oo]);
    }
    __syncthreads();

    const int c = t >> 4, o = t & 15;   // 64 chunks x 16 cols

    // S1: w1-weighted suffix sums within chunk
    {
        float acc = 0.0f;
        #pragma unroll
        for (int jj = CHN - 1; jj >= 0; --jj) {
            int j = c * CHN + jj;
            if (j < NNODE) {
                acc = fmaf(w1s[j], Vs[o * NP + j], acc);
                S1[o * NP + j] = acc;
            }
        }
        CT[c][o] = acc;
    }
    __syncthreads();
    // tree-scan CT into inclusive SUFFIX sums over c (6 steps)
    #pragma unroll
    for (int s = 1; s < 64; s <<= 1) {
        float add = (c + s < 64) ? CT[c + s][o] : 0.0f;
        __syncthreads();
        CT[c][o] += add;
        __syncthreads();
    }
    {
        float off = (c < 63) ? CT[c + 1][o] : 0.0f;
        #pragma unroll
        for (int jj = 0; jj < CHN; ++jj) {
            int j = c * CHN + jj;
            if (j < NNODE) S1[o * NP + j] += off;
        }
        if (c == 0) S1[o * NP + NNODE] = 0.0f;
    }
    // S2: w2-weighted exclusive prefix within chunk, in place over Vs
    {
        float acc = 0.0f;
        #pragma unroll
        for (int jj = 0; jj < CHN; ++jj) {
            int j = c * CHN + jj;
            if (j < NNODE) {
                float tmp = Vs[o * NP + j];
                Vs[o * NP + j] = acc;
                acc = fmaf(w2s[j], tmp, acc);
            }
        }
        CT2[c][o] = acc;
    }
    __syncthreads();
    // tree-scan CT2 into inclusive PREFIX sums over c (6 steps)
    #pragma unroll
    for (int s = 1; s < 64; s <<= 1) {
        float add = (c >= s) ? CT2[c - s][o] : 0.0f;
        __syncthreads();
        CT2[c][o] += add;
        __syncthreads();
    }
    {
        float off = (c > 0) ? CT2[c - 1][o] : 0.0f;
        #pragma unroll
        for (int jj = 0; jj < CHN; ++jj) {
            int j = c * CHN + jj;
            if (j < NNODE) Vs[o * NP + j] += off;
        }
        if (c == 63) Vs[o * NP + NNODE] = CT2[63][o];
    }
    __syncthreads();

    // emit: float4 per (row, col-quad)
    for (int idx = t; idx < NNODE * 4; idx += 1024) {
        int n = idx >> 2, q = (idx & 3) * 4;
        int tt = tls[n];
        float g1 = g1s[n], g2 = g2s[n];
        float r[4];
        #pragma unroll
        for (int rr = 0; rr < 4; ++rr) {
            int oo = q + rr;
            float v = g1 * S1[oo * NP + tt] + g2 * Vs[oo * NP + tt] + biasl[oo];
            r[rr] = (v > 0.0f) ? v : (__expf(v) - 1.0f);
        }
        *(float4*)(out + ((long)b * NNODE + n) * HO + c0 + q) =
            make_float4(r[0], r[1], r[2], r[3]);
    }
}

extern "C" void kernel_launch(void* const* d_in, const int* in_sizes, int n_in,
                              void* d_out, int out_size, void* d_ws, size_t ws_size,
                              hipStream_t stream) {
    const float* x     = (const float*)d_in[0];   // [108,392,256]
    const float* w_mlp = (const float*)d_in[2];   // [256,256]
    const float* b_mlp = (const float*)d_in[3];   // [256]
    const float* kern  = (const float*)d_in[4];   // [256,4,64] == [256,256]
    const float* ask   = (const float*)d_in[5];   // [64,4,1]
    const float* ank   = (const float*)d_in[6];   // [64,4,1]
    const float* bias  = (const float*)d_in[7];   // [256]
    float* out = (float*)d_out;

    const long TENS = (long)MROWS * IDIM;         // 10,838,016
    float*  s0    = (float*)d_ws;                 // [B,H,N]
    float*  ng0   = s0 + SGH;
    float*  zbacc = ng0 + SGH;                    // [B,256] atomically built
    float*  zbK   = zbacc + (long)BATCH * IDIM;   // [B,256]
    float*  sb    = zbK + (long)BATCH * HO;       // [B,H]
    float*  ngb   = sb + BATCH * HEADS;           // [B,H]
    float2* w12G  = (float2*)(ngb + BATCH * HEADS);
    float2* g12G  = w12G + SGH;
    uint*   ptG   = (uint*)(g12G + SGH);
    ushort* xp_bf = (ushort*)(ptG + SGH);         // [B,N,H*O] bf16 (xp0)
    ushort* wshuf = xp_bf + TENS;                 // [65536] frag-order w_mlp
    ushort* kshuf = wshuf + 65536;                // [65536] frag-order kernel

    dim3 blk(256);

    // 0) weight shuffle + zbacc zeroing (fused)
    wcvt<<<dim3(512), blk, 0, stream>>>(w_mlp, kern, wshuf, kshuf, zbacc);

    // 1) fused: mlp(sigmoid, LDS-only) -> col-sums -> xp0 + s0/ng0
    //    R3: 32-row tiles, 256 thr, grid 13x108 (occupancy was grid-capped at 26%)
    fused_gemm<<<dim3(13, BATCH), dim3(256), 0, stream>>>(
        x, wshuf, kshuf, b_mlp, zbacc, xp_bf, ask, ank, s0, ng0);

    // 2) zbK = (0.8*mean mlp) @ kernel + per-(b,h) projection constants
    zbk_k<<<dim3(BATCH), dim3(1024), 0, stream>>>(zbacc, kern, ask, ank, zbK, sb, ngb);

    // 3) attention stats: const-shifted sort + denominators + thresholds
    attn_stats<<<dim3(BATCH * HEADS), dim3(512), 0, stream>>>(
        s0, ng0, sb, ngb, ptG, w12G, g12G);

    // 4) attention scan: tree-scanned prefix/suffix sums + emit
    attn_scan<<<dim3(4, BATCH * HEADS), dim3(1024), 0, stream>>>(
        xp_bf, ptG, w12G, g12G, zbK, bias, out);
}